// Round 1
// baseline (344.270 us; speedup 1.0000x reference)
//
#include <hip/hip_runtime.h>
#include <math.h>

#define W 480
#define HT 480
#define HW (W*HT)
#define GE (HW/256)
#define PP 225
#define NPATCH 1024
#define EQCAP 8192

struct State {
  unsigned hist[256];
  unsigned tk_prefix, tk_k;   // top-k select state (descending, k=230)
  unsigned pc_prefix, pc_k;   // percentile select state (ascending, rank 11521)
  float sumA[3];
  unsigned eqCount;
  float A[3];
  unsigned eqIdx[EQCAP];
  float tp1[NPATCH];
  float tp2[NPATCH];
};

// ---------------- init (ws is re-poisoned 0xAA before every launch) ----------------
__global__ __launch_bounds__(256) void k_init(State* st) {
  int t = threadIdx.x;
  st->hist[t] = 0u;
  if (t == 0) {
    st->tk_prefix = 0u; st->tk_k = 230u;      // k = int(480*480*0.001)
    st->pc_prefix = 0u; st->pc_k = 11521u;    // 1-based rank of sorted[11520]
    st->sumA[0] = 0.f; st->sumA[1] = 0.f; st->sumA[2] = 0.f;
    st->eqCount = 0u;
  }
}

// ---------------- dark channel: channel min + separable 55-min (pad 1.0) ----------------
__global__ __launch_bounds__(256) void k_dmin(const float* __restrict__ img, float* __restrict__ out) {
  int p = blockIdx.x * 256 + threadIdx.x;
  out[p] = fminf(fminf(img[p], img[HW + p]), img[2 * HW + p]);
}

__global__ __launch_bounds__(256) void k_minH(const float* __restrict__ in, float* __restrict__ out) {
  int p = blockIdx.x * 256 + threadIdx.x;
  int y = p / W, x = p - y * W;
  float m = INFINITY;
  for (int d = -27; d <= 27; ++d) {
    int xx = x + d;
    float v = ((unsigned)xx < (unsigned)W) ? in[y * W + xx] : 1.0f;
    m = fminf(m, v);
  }
  out[p] = m;
}

__global__ __launch_bounds__(256) void k_minV(const float* __restrict__ in, float* __restrict__ out) {
  int p = blockIdx.x * 256 + threadIdx.x;
  int y = p / W, x = p - y * W;
  float m = INFINITY;
  for (int d = -27; d <= 27; ++d) {
    int yy = y + d;
    float v = ((unsigned)yy < (unsigned)HT) ? in[yy * W + x] : 1.0f;
    m = fminf(m, v);
  }
  out[p] = m;
}

// ---------------- byte-radix select (exact k-th order statistic on non-negative floats) ----------------
__global__ __launch_bounds__(256) void k_hist(const float* __restrict__ data,
                                              unsigned* __restrict__ hist,
                                              const unsigned* __restrict__ prefix_p,
                                              unsigned mask, int shift, int z2t) {
  __shared__ unsigned lh[256];
  lh[threadIdx.x] = 0u;
  __syncthreads();
  int p = blockIdx.x * 256 + threadIdx.x;
  float v = data[p];
  if (z2t) v = (v > 0.0f) ? v : 10.0f;   // where(t>0, t, 10.0); NaN -> 10
  unsigned bits = __float_as_uint(v);
  unsigned pref = *prefix_p;
  if ((bits & mask) == (pref & mask))
    atomicAdd(&lh[(bits >> shift) & 0xFFu], 1u);
  __syncthreads();
  unsigned c = lh[threadIdx.x];
  if (c) atomicAdd(&hist[threadIdx.x], c);
}

__global__ __launch_bounds__(256) void k_resolve(unsigned* __restrict__ hist,
                                                 unsigned* __restrict__ prefix,
                                                 unsigned* __restrict__ kp,
                                                 int shift, int desc) {
  int t = threadIdx.x;
  if (t == 0) {
    unsigned k = *kp, cum = 0u, chosen = 0u;
    if (desc) {
      for (int b = 255; b >= 0; --b) {
        unsigned c = hist[b];
        if (cum + c >= k) { chosen = (unsigned)b; break; }
        cum += c;
      }
    } else {
      for (int b = 0; b < 256; ++b) {
        unsigned c = hist[b];
        if (cum + c >= k) { chosen = (unsigned)b; break; }
        cum += c;
      }
    }
    *prefix = *prefix | (chosen << shift);
    *kp = k - cum;   // rank within the chosen bucket (>=1)
  }
  __syncthreads();
  hist[t] = 0u;      // ready for next pass / next select
}

// ---------------- airlight gather: dc > v* always; dc == v* -> candidate list ----------------
__global__ __launch_bounds__(256) void k_gatherA(const float* __restrict__ dc,
                                                 const float* __restrict__ img, State* st) {
  int p = blockIdx.x * 256 + threadIdx.x;
  unsigned bits = __float_as_uint(dc[p]);
  unsigned vb = st->tk_prefix;
  if (bits > vb) {
    atomicAdd(&st->sumA[0], img[p]);
    atomicAdd(&st->sumA[1], img[HW + p]);
    atomicAdd(&st->sumA[2], img[2 * HW + p]);
  } else if (bits == vb) {
    unsigned pos = atomicAdd(&st->eqCount, 1u);
    if (pos < (unsigned)EQCAP) st->eqIdx[pos] = (unsigned)p;
  }
}

// lax.top_k tie-break: lower index first -> take the (tk_k) smallest indices among equals
__global__ __launch_bounds__(256) void k_finalizeA(const float* __restrict__ img, State* st) {
  __shared__ unsigned sIdx[EQCAP];
  __shared__ float ssum[3];
  int t = threadIdx.x;
  unsigned ne = st->eqCount; if (ne > (unsigned)EQCAP) ne = EQCAP;
  unsigned keq = st->tk_k;
  for (int i = t; i < EQCAP; i += 256) sIdx[i] = (i < (int)ne) ? st->eqIdx[i] : 0xFFFFFFFFu;
  if (t < 3) ssum[t] = 0.f;
  __syncthreads();
  float a0 = 0.f, a1 = 0.f, a2 = 0.f;
  for (int i = t; i < (int)ne; i += 256) {
    unsigned my = sIdx[i];
    unsigned rank = 0u;
    for (int j = 0; j < (int)ne; ++j) rank += (sIdx[j] < my) ? 1u : 0u;
    if (rank < keq) { a0 += img[my]; a1 += img[HW + my]; a2 += img[2 * HW + my]; }
  }
  atomicAdd(&ssum[0], a0); atomicAdd(&ssum[1], a1); atomicAdd(&ssum[2], a2);
  __syncthreads();
  if (t == 0) {
    st->A[0] = (st->sumA[0] + ssum[0]) / 230.0f;
    st->A[1] = (st->sumA[1] + ssum[1]) / 230.0f;
    st->A[2] = (st->sumA[2] + ssum[2]) / 230.0f;
  }
}

// ---------------- S, V1, I, and bccr pre-pool map in one pass ----------------
__global__ __launch_bounds__(256) void k_elem1(const float* __restrict__ img,
                                               const State* __restrict__ st,
                                               float* __restrict__ So, float* __restrict__ Vo,
                                               float* __restrict__ Io, float* __restrict__ To) {
  int p = blockIdx.x * 256 + threadIdx.x;
  float A0 = st->A[0], A1 = st->A[1], A2 = st->A[2];
  float r = img[p], g = img[HW + p], bl = img[2 * HW + p];
  float nr = r / A0, ng = g / A1, nb = bl / A2;
  float mx = fmaxf(fmaxf(nr, ng), nb);
  float mn = fminf(fminf(nr, ng), nb);
  float d = mx + 1e-8f;
  So[p] = 1.0f - mn / d;
  Vo[p] = 1.0f / d;
  Io[p] = ((r + g) + bl) / 3.0f;
  const float c20 = (float)(20.0 / 255.0);
  const float c300 = (float)(300.0 / 255.0);
  float t0 = fmaxf((A0 - r) / (A0 - c20), (A0 - r) / (A0 - c300));
  float t1 = fmaxf((A1 - g) / (A1 - c20), (A1 - g) / (A1 - c300));
  float t2 = fmaxf((A2 - bl) / (A2 - c20), (A2 - bl) / (A2 - c300));
  To[p] = fmaxf(fmaxf(t0, t1), t2);
}

// ---------------- per-patch SLP regression ----------------
__device__ __forceinline__ float bred_sum(float* red, int t, float v) {
  __syncthreads(); red[t] = v; __syncthreads();
  for (int s = 128; s > 0; s >>= 1) { if (t < s) red[t] += red[t + s]; __syncthreads(); }
  return red[0];
}
__device__ __forceinline__ float bred_max(float* red, int t, float v) {
  __syncthreads(); red[t] = v; __syncthreads();
  for (int s = 128; s > 0; s >>= 1) { if (t < s) red[t] = fmaxf(red[t], red[t + s]); __syncthreads(); }
  return red[0];
}
__device__ __forceinline__ float bred_min(float* red, int t, float v) {
  __syncthreads(); red[t] = v; __syncthreads();
  for (int s = 128; s > 0; s >>= 1) { if (t < s) red[t] = fminf(red[t], red[t + s]); __syncthreads(); }
  return red[0];
}

__global__ __launch_bounds__(256) void k_patch(const float* __restrict__ Sv,
                                               const float* __restrict__ Vv,
                                               float* __restrict__ tp, int mode) {
  __shared__ float Xs[PP], Ys[PP];
  __shared__ float red[256];
  int t = threadIdx.x;
  int pid = blockIdx.x;
  int ph = pid >> 5, pw = pid & 31;
  if (t < PP) {
    int r = t / 15, c = t - (t / 15) * 15;
    int y, x;
    if (mode == 0) { y = ph * 15 + r; x = pw * 15 + c; }
    else {
      // crop [7:,7:], edge-pad 3 top/left, 4 bottom/right: orig = clamp(pr+4, 7, 479)
      y = ph * 15 + r + 4; y = (y < 7) ? 7 : ((y > 479) ? 479 : y);
      x = pw * 15 + c + 4; x = (x < 7) ? 7 : ((x > 479) ? 479 : x);
    }
    Xs[t] = Vv[y * W + x];
    Ys[t] = Sv[y * W + x];
  }
  __syncthreads();
  float xi = 0.f, yi = 0.f;
  int cnt = 0;
  if (t < PP) {
    xi = Xs[t]; yi = Ys[t];
    for (int j = 0; j < PP; ++j) {
      float sl = (yi - Ys[j]) / ((xi - Xs[j]) + 1e-8f);
      if (sl > -1.0f && sl < 0.0f) ++cnt;
    }
  }
  float pmf = (t < PP && cnt >= 113) ? 1.0f : 0.0f;   // scount >= 0.5*225 = 112.5
  float xm = xi * pmf, ym = yi * pmf;
  float pcount = bred_sum(red, t, pmf);
  float sx  = bred_sum(red, t, xm);
  float sy  = bred_sum(red, t, ym);
  float sxy = bred_sum(red, t, xm * ym);
  float sxx = bred_sum(red, t, xm * xm);
  float mxX = bred_max(red, t, (t < PP) ? xm : -INFINITY);
  float mnX = bred_min(red, t, (t < PP) ? (xi + 1e8f * (1.0f - pmf)) : INFINITY);
  if (t == 0) {
    float den = pcount + 1e-5f;
    float mxv = sx / den, myv = sy / den;
    float kk = (sxy - pcount * mxv * myv) / (sxx - pcount * (mxv * mxv) + 1e-5f);
    float bb = myv - kk * mxv;
    float tt = 1.0f + kk / (bb + 1e-8f);
    float len = sqrtf(1.0f + kk * kk) * (mxX - mnX);
    bool m = (pcount > 10.0f) && (len > 0.1f) && (kk > -1.0f) && (kk < 0.0f)
             && (tt > 0.01f) && (tt < 0.99f);
    tp[pid] = tt * (m ? 1.0f : 0.0f);   // keeps JAX's NaN*0 semantics
  }
}

// ---------------- t_slp fusion of the two shifted patch grids ----------------
__global__ __launch_bounds__(256) void k_tslp(const State* __restrict__ st, float* __restrict__ out) {
  int p = blockIdx.x * 256 + threadIdx.x;
  int y = p / W, x = p - y * W;
  float a = st->tp1[(y / 15) * 32 + (x / 15)];
  float b = 0.0f;
  if (y >= 7 && x >= 7) b = st->tp2[((y - 4) / 15) * 32 + ((x - 4) / 15)];
  float r;
  if (a != 0.0f && b != 0.0f) r = (a + b) / 2.0f;   // NaN != 0 is true, as in JAX
  else r = (a != 0.0f) ? a : b;
  out[p] = r;
}

// ---------------- bccr 15x15 max pool (pad 0) + clip ----------------
__global__ __launch_bounds__(256) void k_maxH(const float* __restrict__ in, float* __restrict__ out) {
  int p = blockIdx.x * 256 + threadIdx.x;
  int y = p / W, x = p - y * W;
  float m = -INFINITY;
  for (int d = -7; d <= 7; ++d) {
    int xx = x + d;
    float v = ((unsigned)xx < (unsigned)W) ? in[y * W + xx] : 0.0f;
    m = fmaxf(m, v);
  }
  out[p] = m;
}

__global__ __launch_bounds__(256) void k_maxVclip(const float* __restrict__ in, float* __restrict__ out) {
  int p = blockIdx.x * 256 + threadIdx.x;
  int y = p / W, x = p - y * W;
  float m = -INFINITY;
  for (int d = -7; d <= 7; ++d) {
    int yy = y + d;
    float v = ((unsigned)yy < (unsigned)HT) ? in[yy * W + x] : 0.0f;
    m = fmaxf(m, v);
  }
  out[p] = fminf(fmaxf(m, 0.05f), 1.0f);
}

// ---------------- t_fusion ----------------
__global__ __launch_bounds__(256) void k_fusion(const float* __restrict__ ts,
                                                const float* __restrict__ tb,
                                                const State* __restrict__ st,
                                                float* __restrict__ out) {
  int p = blockIdx.x * 256 + threadIdx.x;
  float x = ts[p];
  float v = (x > 0.0f) ? x : tb[p];
  float tmin = __uint_as_float(st->pc_prefix);
  v = (v < tmin) ? tmin : v;   // clip(v, tmin, 1) incl. tmin>1 degenerate case
  v = (v > 1.0f) ? 1.0f : v;
  out[p] = v;
}

// ---------------- guided filter r=30 eps=1e-3, separable box passes ----------------
__global__ __launch_bounds__(256) void k_gf1h(const float* __restrict__ I, const float* __restrict__ P,
                                              float* __restrict__ oI, float* __restrict__ oP,
                                              float* __restrict__ oIp, float* __restrict__ oII) {
  int p = blockIdx.x * 256 + threadIdx.x;
  int y = p / W, x = p - y * W;
  float sI = 0.f, sP = 0.f, sIp = 0.f, sII = 0.f;
  for (int d = -30; d <= 30; ++d) {
    int xx = x + d;
    if ((unsigned)xx < (unsigned)W) {
      float iv = I[y * W + xx], pv = P[y * W + xx];
      sI += iv; sP += pv; sIp += iv * pv; sII += iv * iv;
    }
  }
  oI[p] = sI; oP[p] = sP; oIp[p] = sIp; oII[p] = sII;
}

__global__ __launch_bounds__(256) void k_gf1v(const float* __restrict__ hI, const float* __restrict__ hP,
                                              const float* __restrict__ hIp, const float* __restrict__ hII,
                                              float* __restrict__ ao, float* __restrict__ bo) {
  int p = blockIdx.x * 256 + threadIdx.x;
  int y = p / W, x = p - y * W;
  float sI = 0.f, sP = 0.f, sIp = 0.f, sII = 0.f;
  for (int d = -30; d <= 30; ++d) {
    int yy = y + d;
    if ((unsigned)yy < (unsigned)HT) {
      int q = yy * W + x;
      sI += hI[q]; sP += hP[q]; sIp += hIp[q]; sII += hII[q];
    }
  }
  int ny = min(y + 30, HT - 1) - max(y - 30, 0) + 1;
  int nx = min(x + 30, W - 1) - max(x - 30, 0) + 1;
  float Nn = (float)(ny * nx);
  float mI = sI / Nn, mP = sP / Nn, mIp = sIp / Nn, mII = sII / Nn;
  float cov = mIp - mI * mP;
  float var = mII - mI * mI;
  float av = cov / (var + 1e-3f);
  ao[p] = av;
  bo[p] = mP - av * mI;
}

__global__ __launch_bounds__(256) void k_gf2h(const float* __restrict__ a, const float* __restrict__ b,
                                              float* __restrict__ oa, float* __restrict__ ob) {
  int p = blockIdx.x * 256 + threadIdx.x;
  int y = p / W, x = p - y * W;
  float sa = 0.f, sb = 0.f;
  for (int d = -30; d <= 30; ++d) {
    int xx = x + d;
    if ((unsigned)xx < (unsigned)W) { sa += a[y * W + xx]; sb += b[y * W + xx]; }
  }
  oa[p] = sa; ob[p] = sb;
}

__global__ __launch_bounds__(256) void k_gf2vfin(const float* __restrict__ ha, const float* __restrict__ hb,
                                                 const float* __restrict__ I, const float* __restrict__ img,
                                                 const State* __restrict__ st, float* __restrict__ out) {
  int p = blockIdx.x * 256 + threadIdx.x;
  int y = p / W, x = p - y * W;
  float sa = 0.f, sb = 0.f;
  for (int d = -30; d <= 30; ++d) {
    int yy = y + d;
    if ((unsigned)yy < (unsigned)HT) { int q = yy * W + x; sa += ha[q]; sb += hb[q]; }
  }
  int ny = min(y + 30, HT - 1) - max(y - 30, 0) + 1;
  int nx = min(x + 30, W - 1) - max(x - 30, 0) + 1;
  float Nn = (float)(ny * nx);
  float tref = (sa / Nn) * I[p] + (sb / Nn);
  float A0 = st->A[0], A1 = st->A[1], A2 = st->A[2];
  out[p]           = (img[p]           - A0) / tref + A0;
  out[HW + p]      = (img[HW + p]      - A1) / tref + A1;
  out[2 * HW + p]  = (img[2 * HW + p]  - A2) / tref + A2;
}

// ---------------- launch ----------------
extern "C" void kernel_launch(void* const* d_in, const int* in_sizes, int n_in,
                              void* d_out, int out_size, void* d_ws, size_t ws_size,
                              hipStream_t stream) {
  (void)in_sizes; (void)n_in; (void)out_size; (void)ws_size;
  const float* img = (const float*)d_in[0];
  float* out = (float*)d_out;
  State* st = (State*)d_ws;
  float* sb = (float*)((char*)d_ws + 65536);
  float* s0 = sb + 0 * HW;  // dmin -> dc -> t_slp
  float* s1 = sb + 1 * HW;  // dark H temp -> bccr map -> t_bl
  float* s2 = sb + 2 * HW;  // S -> a
  float* s3 = sb + 3 * HW;  // V1 -> b
  float* s4 = sb + 4 * HW;  // I (channel mean)
  float* s5 = sb + 5 * HW;  // pool temp -> t_fusion
  float* s6 = sb + 6 * HW;  // box temps
  float* s7 = sb + 7 * HW;
  float* s8 = sb + 8 * HW;
  float* s9 = sb + 9 * HW;

  dim3 blk(256);
  dim3 ge(GE);
  const unsigned masks[4] = {0x00000000u, 0xFF000000u, 0xFFFF0000u, 0xFFFFFF00u};
  const int shifts[4] = {24, 16, 8, 0};

  k_init<<<dim3(1), blk, 0, stream>>>(st);

  // dark channel
  k_dmin<<<ge, blk, 0, stream>>>(img, s0);
  k_minH<<<ge, blk, 0, stream>>>(s0, s1);
  k_minV<<<ge, blk, 0, stream>>>(s1, s0);

  // exact top-230 value (descending radix select)
  for (int i = 0; i < 4; ++i) {
    k_hist<<<ge, blk, 0, stream>>>(s0, st->hist, &st->tk_prefix, masks[i], shifts[i], 0);
    k_resolve<<<dim3(1), blk, 0, stream>>>(st->hist, &st->tk_prefix, &st->tk_k, shifts[i], 1);
  }
  k_gatherA<<<ge, blk, 0, stream>>>(s0, img, st);
  k_finalizeA<<<dim3(1), blk, 0, stream>>>(img, st);

  // S, V1, I, bccr map
  k_elem1<<<ge, blk, 0, stream>>>(img, st, s2, s3, s4, s1);

  // patch regressions (t1 grid + shifted t2 grid)
  k_patch<<<dim3(NPATCH), blk, 0, stream>>>(s2, s3, st->tp1, 0);
  k_patch<<<dim3(NPATCH), blk, 0, stream>>>(s2, s3, st->tp2, 1);
  k_tslp<<<ge, blk, 0, stream>>>(st, s0);

  // bccr 15x15 max pool + clip
  k_maxH<<<ge, blk, 0, stream>>>(s1, s5);
  k_maxVclip<<<ge, blk, 0, stream>>>(s5, s1);

  // exact 5th-percentile value (ascending radix select on where(t>0,t,10))
  for (int i = 0; i < 4; ++i) {
    k_hist<<<ge, blk, 0, stream>>>(s0, st->hist, &st->pc_prefix, masks[i], shifts[i], 1);
    k_resolve<<<dim3(1), blk, 0, stream>>>(st->hist, &st->pc_prefix, &st->pc_k, shifts[i], 0);
  }

  // fusion + guided filter + restore
  k_fusion<<<ge, blk, 0, stream>>>(s0, s1, st, s5);
  k_gf1h<<<ge, blk, 0, stream>>>(s4, s5, s6, s7, s8, s9);
  k_gf1v<<<ge, blk, 0, stream>>>(s6, s7, s8, s9, s2, s3);
  k_gf2h<<<ge, blk, 0, stream>>>(s2, s3, s6, s7);
  k_gf2vfin<<<ge, blk, 0, stream>>>(s6, s7, s4, img, st, out);
}

// Round 2
// 309.563 us; speedup vs baseline: 1.1121x; 1.1121x over previous
//
#include <hip/hip_runtime.h>
#include <math.h>

#define W 480
#define HT 480
#define HW (W*HT)
#define GE (HW/256)     // 900 blocks of 256
#define PP 225
#define NPATCH 1024
#define EQCAP 8192

struct State {
  unsigned histA[4][256];   // dark-channel top-k select (descending, k=230)
  unsigned histB[4][256];   // percentile select (ascending, rank 11521)
  float sumA[3];
  unsigned eqCount;
  float A[3];
  unsigned eqIdx[EQCAP];
  float tp1[NPATCH];
  float tp2[NPATCH];
};

// ---------- cooperative radix-select resolve (replaces serial k_resolve kernels) ----------
// All 256 threads participate; lds must have >= 258 slots.
__device__ __forceinline__ void resolve_level(const unsigned* __restrict__ h,
                                              unsigned k_in, int desc,
                                              unsigned* lds,
                                              unsigned& chosen, unsigned& k_out) {
  int t = threadIdx.x;
  unsigned c = h[desc ? (255 - t) : t];
  lds[t] = c;
  __syncthreads();
  for (int s = 1; s < 256; s <<= 1) {           // Hillis-Steele inclusive scan
    unsigned add = (t >= s) ? lds[t - s] : 0u;
    __syncthreads();
    lds[t] += add;
    __syncthreads();
  }
  unsigned incl = lds[t];
  unsigned excl = incl - c;
  if (incl >= k_in && excl < k_in) { lds[256] = (unsigned)t; lds[257] = k_in - excl; }
  __syncthreads();
  unsigned tt = lds[256];
  k_out = lds[257];
  chosen = desc ? (255u - tt) : tt;
  __syncthreads();
}

__device__ __forceinline__ void resolve_prefix(const unsigned (*hist)[256], unsigned k0,
                                               int desc, int levels, unsigned* lds,
                                               unsigned& bits, unsigned& kf) {
  unsigned prefix = 0u, k = k0;
  for (int j = 0; j < levels; ++j) {
    unsigned ch, kn;
    resolve_level(hist[j], k, desc, lds, ch, kn);
    prefix |= ch << (24 - 8 * j);
    k = kn;
  }
  bits = prefix; kf = k;
}

// ---------- stage 0: init state + channel-min ----------
__global__ __launch_bounds__(256) void k0_init_dmin(const float* __restrict__ img,
                                                    float* __restrict__ out, State* st) {
  int t = threadIdx.x;
  int p = blockIdx.x * 256 + t;
  out[p] = fminf(fminf(img[p], img[HW + p]), img[2 * HW + p]);
  if (blockIdx.x == 0) {
    for (int i = 0; i < 4; ++i) { st->histA[i][t] = 0u; st->histB[i][t] = 0u; }
    if (t == 0) { st->sumA[0] = 0.f; st->sumA[1] = 0.f; st->sumA[2] = 0.f; st->eqCount = 0u; }
  }
}

// ---------- separable 55-min (pad 1.0) ----------
__global__ __launch_bounds__(256) void k_minH(const float* __restrict__ in, float* __restrict__ out) {
  int p = blockIdx.x * 256 + threadIdx.x;
  int y = p / W, x = p - y * W;
  float m = INFINITY;
  for (int d = -27; d <= 27; ++d) {
    int xx = x + d;
    float v = ((unsigned)xx < (unsigned)W) ? in[y * W + xx] : 1.0f;
    m = fminf(m, v);
  }
  out[p] = m;
}
__global__ __launch_bounds__(256) void k_minV(const float* __restrict__ in, float* __restrict__ out) {
  int p = blockIdx.x * 256 + threadIdx.x;
  int y = p / W, x = p - y * W;
  float m = INFINITY;
  for (int d = -27; d <= 27; ++d) {
    int yy = y + d;
    float v = ((unsigned)yy < (unsigned)HT) ? in[yy * W + x] : 1.0f;
    m = fminf(m, v);
  }
  out[p] = m;
}

// ---------- radix histogram pass (resolves previous levels cooperatively) ----------
__global__ __launch_bounds__(256) void k_hist(const float* __restrict__ data,
                                              unsigned (*hist)[256],
                                              int level, unsigned k0, int desc, int z2t) {
  __shared__ unsigned lds[258];
  int t = threadIdx.x;
  unsigned prefix = 0u, k = k0;
  for (int j = 0; j < level; ++j) {
    unsigned ch, kn;
    resolve_level(hist[j], k, desc, lds, ch, kn);
    prefix |= ch << (24 - 8 * j);
    k = kn;
  }
  lds[t] = 0u;
  __syncthreads();
  int p = blockIdx.x * 256 + t;
  float v = data[p];
  if (z2t) v = (v > 0.0f) ? v : 10.0f;   // where(t>0, t, 10.0); NaN -> 10
  unsigned bits = __float_as_uint(v);
  bool ok = true;
  if (level > 0) {
    unsigned mask = 0xFFFFFFFFu << (32 - 8 * level);
    ok = (bits & mask) == prefix;
  }
  if (ok) atomicAdd(&lds[(bits >> (24 - 8 * level)) & 0xFFu], 1u);
  __syncthreads();
  unsigned c = lds[t];
  if (c) atomicAdd(&hist[level][t], c);
}

// ---------- airlight gather ----------
__global__ __launch_bounds__(256) void k_gatherA(const float* __restrict__ dc,
                                                 const float* __restrict__ img, State* st) {
  __shared__ unsigned lds[258];
  unsigned vb, kf;
  resolve_prefix(st->histA, 230u, 1, 4, lds, vb, kf);
  int p = blockIdx.x * 256 + threadIdx.x;
  unsigned bits = __float_as_uint(dc[p]);
  if (bits > vb) {
    atomicAdd(&st->sumA[0], img[p]);
    atomicAdd(&st->sumA[1], img[HW + p]);
    atomicAdd(&st->sumA[2], img[2 * HW + p]);
  } else if (bits == vb) {
    unsigned pos = atomicAdd(&st->eqCount, 1u);
    if (pos < (unsigned)EQCAP) st->eqIdx[pos] = (unsigned)p;
  }
}

// lax.top_k tie-break = lower index first: take keq smallest indices among equals
// via cooperative binary search (replaces O(ne^2) ranking).
__global__ __launch_bounds__(256) void k_finalizeA(const float* __restrict__ img, State* st) {
  __shared__ unsigned lds[258];
  __shared__ unsigned sIdx[EQCAP];
  __shared__ float ssum[3];
  unsigned vb, keq;
  resolve_prefix(st->histA, 230u, 1, 4, lds, vb, keq);
  int t = threadIdx.x;
  unsigned ne = st->eqCount; if (ne > (unsigned)EQCAP) ne = EQCAP;
  for (int i = t; i < (int)ne; i += 256) sIdx[i] = st->eqIdx[i];
  if (t < 3) ssum[t] = 0.f;
  __syncthreads();
  // smallest hi such that count(idx < hi) >= keq  (indices distinct -> count == keq)
  unsigned lo = 0u, hi = HW;
  while (hi - lo > 1u) {
    unsigned mid = (lo + hi) >> 1;
    unsigned c = 0u;
    for (int i = t; i < (int)ne; i += 256) c += (sIdx[i] < mid) ? 1u : 0u;
    lds[t] = c; __syncthreads();
    for (int s = 128; s > 0; s >>= 1) { if (t < s) lds[t] += lds[t + s]; __syncthreads(); }
    unsigned total = lds[0];
    __syncthreads();
    if (total >= keq) hi = mid; else lo = mid;
  }
  float a0 = 0.f, a1 = 0.f, a2 = 0.f;
  for (int i = t; i < (int)ne; i += 256) {
    unsigned q = sIdx[i];
    if (q < hi) { a0 += img[q]; a1 += img[HW + q]; a2 += img[2 * HW + q]; }
  }
  atomicAdd(&ssum[0], a0); atomicAdd(&ssum[1], a1); atomicAdd(&ssum[2], a2);
  __syncthreads();
  if (t == 0) {
    st->A[0] = (st->sumA[0] + ssum[0]) / 230.0f;
    st->A[1] = (st->sumA[1] + ssum[1]) / 230.0f;
    st->A[2] = (st->sumA[2] + ssum[2]) / 230.0f;
  }
}

// ---------- S, V1, I, bccr pre-pool map ----------
__global__ __launch_bounds__(256) void k_elem1(const float* __restrict__ img,
                                               const State* __restrict__ st,
                                               float* __restrict__ So, float* __restrict__ Vo,
                                               float* __restrict__ Io, float* __restrict__ To) {
  int p = blockIdx.x * 256 + threadIdx.x;
  float A0 = st->A[0], A1 = st->A[1], A2 = st->A[2];
  float r = img[p], g = img[HW + p], bl = img[2 * HW + p];
  float nr = r / A0, ng = g / A1, nb = bl / A2;
  float mx = fmaxf(fmaxf(nr, ng), nb);
  float mn = fminf(fminf(nr, ng), nb);
  float d = mx + 1e-8f;
  So[p] = 1.0f - mn / d;
  Vo[p] = 1.0f / d;
  Io[p] = ((r + g) + bl) / 3.0f;
  const float c20 = (float)(20.0 / 255.0);
  const float c300 = (float)(300.0 / 255.0);
  float t0 = fmaxf((A0 - r) / (A0 - c20), (A0 - r) / (A0 - c300));
  float t1 = fmaxf((A1 - g) / (A1 - c20), (A1 - g) / (A1 - c300));
  float t2 = fmaxf((A2 - bl) / (A2 - c20), (A2 - bl) / (A2 - c300));
  To[p] = fmaxf(fmaxf(t0, t1), t2);
}

// ---------- wave reductions ----------
__device__ __forceinline__ float wred_sum(float v) { for (int m = 32; m; m >>= 1) v += __shfl_xor(v, m, 64); return v; }
__device__ __forceinline__ float wred_max(float v) { for (int m = 32; m; m >>= 1) v = fmaxf(v, __shfl_xor(v, m, 64)); return v; }
__device__ __forceinline__ float wred_min(float v) { for (int m = 32; m; m >>= 1) v = fminf(v, __shfl_xor(v, m, 64)); return v; }

// ---------- mega1: both patch grids + bccr H-maxpool ----------
__global__ __launch_bounds__(256) void k_mega1(const float* __restrict__ Sv,
                                               const float* __restrict__ Vv,
                                               const float* __restrict__ To,
                                               float* __restrict__ mh, State* st) {
  __shared__ float XY[2 * PP];
  __shared__ float part[4][8];
  int b = blockIdx.x;
  int t = threadIdx.x;
  if (b >= 2048) {   // bccr 15-tap horizontal max (pad 0)
    int p = (b - 2048) * 256 + t;
    int y = p / W, x = p - y * W;
    float m = -INFINITY;
    for (int d = -7; d <= 7; ++d) {
      int xx = x + d;
      float v = ((unsigned)xx < (unsigned)W) ? To[y * W + xx] : 0.0f;
      m = fmaxf(m, v);
    }
    mh[p] = m;
    return;
  }
  int mode = b >> 10;              // 0: t1 grid, 1: shifted t2 grid
  int pid = b & 1023;
  int ph = pid >> 5, pw = pid & 31;
  if (t < PP) {
    int r = t / 15, c = t - (t / 15) * 15;
    int y, x;
    if (mode == 0) { y = ph * 15 + r; x = pw * 15 + c; }
    else {
      y = ph * 15 + r + 4; y = (y < 7) ? 7 : ((y > 479) ? 479 : y);
      x = pw * 15 + c + 4; x = (x < 7) ? 7 : ((x > 479) ? 479 : x);
    }
    XY[2 * t]     = Vv[y * W + x];
    XY[2 * t + 1] = Sv[y * W + x];
  }
  __syncthreads();
  float xi = 0.f, yi = 0.f;
  int cnt = 0;
  if (t < PP) {
    xi = XY[2 * t]; yi = XY[2 * t + 1];
    for (int j = 0; j < PP; ++j) {
      float sl = (yi - XY[2 * j + 1]) / ((xi - XY[2 * j]) + 1e-8f);
      cnt += (sl > -1.0f && sl < 0.0f) ? 1 : 0;
    }
  }
  float pmf = (t < PP && cnt >= 113) ? 1.0f : 0.0f;   // scount >= 112.5
  float xm = xi * pmf, ym = yi * pmf;
  float v0 = wred_sum(pmf);
  float v1 = wred_sum(xm);
  float v2 = wred_sum(ym);
  float v3 = wred_sum(xm * ym);
  float v4 = wred_sum(xm * xm);
  float v5 = wred_max((t < PP) ? xm : -INFINITY);
  float v6 = wred_min((t < PP) ? (xi + 1e8f * (1.0f - pmf)) : INFINITY);
  int wid = t >> 6, lane = t & 63;
  if (lane == 0) {
    part[wid][0] = v0; part[wid][1] = v1; part[wid][2] = v2; part[wid][3] = v3;
    part[wid][4] = v4; part[wid][5] = v5; part[wid][6] = v6;
  }
  __syncthreads();
  if (t == 0) {
    float pcount = 0.f, sx = 0.f, sy = 0.f, sxy = 0.f, sxx = 0.f;
    float mxX = -INFINITY, mnX = INFINITY;
    for (int w2 = 0; w2 < 4; ++w2) {
      pcount += part[w2][0]; sx += part[w2][1]; sy += part[w2][2];
      sxy += part[w2][3]; sxx += part[w2][4];
      mxX = fmaxf(mxX, part[w2][5]); mnX = fminf(mnX, part[w2][6]);
    }
    float den = pcount + 1e-5f;
    float mxv = sx / den, myv = sy / den;
    float kk = (sxy - pcount * mxv * myv) / (sxx - pcount * (mxv * mxv) + 1e-5f);
    float bb = myv - kk * mxv;
    float tt = 1.0f + kk / (bb + 1e-8f);
    float len = sqrtf(1.0f + kk * kk) * (mxX - mnX);
    bool m = (pcount > 10.0f) && (len > 0.1f) && (kk > -1.0f) && (kk < 0.0f)
             && (tt > 0.01f) && (tt < 0.99f);
    float res = tt * (m ? 1.0f : 0.0f);   // keep JAX NaN*0 semantics
    if (mode == 0) st->tp1[pid] = res; else st->tp2[pid] = res;
  }
}

// ---------- mega2: t_slp fusion + bccr V-maxpool+clip ----------
__global__ __launch_bounds__(256) void k_mega2(const State* __restrict__ st,
                                               const float* __restrict__ mh,
                                               float* __restrict__ ts_out,
                                               float* __restrict__ tb_out) {
  int b = blockIdx.x;
  int t = threadIdx.x;
  if (b < GE) {
    int p = b * 256 + t;
    int y = p / W, x = p - y * W;
    float a = st->tp1[(y / 15) * 32 + (x / 15)];
    float bb = 0.0f;
    if (y >= 7 && x >= 7) bb = st->tp2[((y - 4) / 15) * 32 + ((x - 4) / 15)];
    float r;
    if (a != 0.0f && bb != 0.0f) r = (a + bb) / 2.0f;   // NaN != 0 true, as in JAX
    else r = (a != 0.0f) ? a : bb;
    ts_out[p] = r;
  } else {
    int p = (b - GE) * 256 + t;
    int y = p / W, x = p - y * W;
    float m = -INFINITY;
    for (int d = -7; d <= 7; ++d) {
      int yy = y + d;
      float v = ((unsigned)yy < (unsigned)HT) ? mh[yy * W + x] : 0.0f;
      m = fmaxf(m, v);
    }
    tb_out[p] = fminf(fmaxf(m, 0.05f), 1.0f);
  }
}

// ---------- t_fusion (resolves percentile prefix cooperatively) ----------
__global__ __launch_bounds__(256) void k_fusion(const float* __restrict__ ts,
                                                const float* __restrict__ tb,
                                                const State* __restrict__ st,
                                                float* __restrict__ out) {
  __shared__ unsigned lds[258];
  unsigned vb, kf;
  resolve_prefix(st->histB, 11521u, 0, 4, lds, vb, kf);
  float tmin = __uint_as_float(vb);
  int p = blockIdx.x * 256 + threadIdx.x;
  float x = ts[p];
  float v = (x > 0.0f) ? x : tb[p];
  v = (v < tmin) ? tmin : v;
  v = (v > 1.0f) ? 1.0f : v;
  out[p] = v;
}

// ---------- guided filter r=30 eps=1e-3 ----------
__global__ __launch_bounds__(256) void k_gf1h(const float* __restrict__ I, const float* __restrict__ P,
                                              float* __restrict__ oI, float* __restrict__ oP,
                                              float* __restrict__ oIp, float* __restrict__ oII) {
  int p = blockIdx.x * 256 + threadIdx.x;
  int y = p / W, x = p - y * W;
  float sI = 0.f, sP = 0.f, sIp = 0.f, sII = 0.f;
  for (int d = -30; d <= 30; ++d) {
    int xx = x + d;
    if ((unsigned)xx < (unsigned)W) {
      float iv = I[y * W + xx], pv = P[y * W + xx];
      sI += iv; sP += pv; sIp += iv * pv; sII += iv * iv;
    }
  }
  oI[p] = sI; oP[p] = sP; oIp[p] = sIp; oII[p] = sII;
}

__global__ __launch_bounds__(256) void k_gf1v(const float* __restrict__ hI, const float* __restrict__ hP,
                                              const float* __restrict__ hIp, const float* __restrict__ hII,
                                              float* __restrict__ ao, float* __restrict__ bo) {
  int p = blockIdx.x * 256 + threadIdx.x;
  int y = p / W, x = p - y * W;
  float sI = 0.f, sP = 0.f, sIp = 0.f, sII = 0.f;
  for (int d = -30; d <= 30; ++d) {
    int yy = y + d;
    if ((unsigned)yy < (unsigned)HT) {
      int q = yy * W + x;
      sI += hI[q]; sP += hP[q]; sIp += hIp[q]; sII += hII[q];
    }
  }
  int ny = min(y + 30, HT - 1) - max(y - 30, 0) + 1;
  int nx = min(x + 30, W - 1) - max(x - 30, 0) + 1;
  float Nn = (float)(ny * nx);
  float mI = sI / Nn, mP = sP / Nn, mIp = sIp / Nn, mII = sII / Nn;
  float cov = mIp - mI * mP;
  float var = mII - mI * mI;
  float av = cov / (var + 1e-3f);
  ao[p] = av;
  bo[p] = mP - av * mI;
}

__global__ __launch_bounds__(256) void k_gf2h(const float* __restrict__ a, const float* __restrict__ b,
                                              float* __restrict__ oa, float* __restrict__ ob) {
  int p = blockIdx.x * 256 + threadIdx.x;
  int y = p / W, x = p - y * W;
  float sa = 0.f, sb = 0.f;
  for (int d = -30; d <= 30; ++d) {
    int xx = x + d;
    if ((unsigned)xx < (unsigned)W) { sa += a[y * W + xx]; sb += b[y * W + xx]; }
  }
  oa[p] = sa; ob[p] = sb;
}

__global__ __launch_bounds__(256) void k_gf2vfin(const float* __restrict__ ha, const float* __restrict__ hb,
                                                 const float* __restrict__ I, const float* __restrict__ img,
                                                 const State* __restrict__ st, float* __restrict__ out) {
  int p = blockIdx.x * 256 + threadIdx.x;
  int y = p / W, x = p - y * W;
  float sa = 0.f, sb = 0.f;
  for (int d = -30; d <= 30; ++d) {
    int yy = y + d;
    if ((unsigned)yy < (unsigned)HT) { int q = yy * W + x; sa += ha[q]; sb += hb[q]; }
  }
  int ny = min(y + 30, HT - 1) - max(y - 30, 0) + 1;
  int nx = min(x + 30, W - 1) - max(x - 30, 0) + 1;
  float Nn = (float)(ny * nx);
  float tref = (sa / Nn) * I[p] + (sb / Nn);
  float A0 = st->A[0], A1 = st->A[1], A2 = st->A[2];
  out[p]          = (img[p]          - A0) / tref + A0;
  out[HW + p]     = (img[HW + p]     - A1) / tref + A1;
  out[2 * HW + p] = (img[2 * HW + p] - A2) / tref + A2;
}

// ---------- launch: 21 dispatches ----------
extern "C" void kernel_launch(void* const* d_in, const int* in_sizes, int n_in,
                              void* d_out, int out_size, void* d_ws, size_t ws_size,
                              hipStream_t stream) {
  (void)in_sizes; (void)n_in; (void)out_size; (void)ws_size;
  const float* img = (const float*)d_in[0];
  float* out = (float*)d_out;
  State* st = (State*)d_ws;
  float* sb = (float*)((char*)d_ws + 65536);
  float* s0 = sb + 0 * HW;  // dmin -> dc -> t_slp
  float* s1 = sb + 1 * HW;  // minH temp -> bccr map -> t_bl
  float* s2 = sb + 2 * HW;  // S -> a
  float* s3 = sb + 3 * HW;  // V1 -> b
  float* s4 = sb + 4 * HW;  // I (channel mean)
  float* s5 = sb + 5 * HW;  // maxH temp -> t_fusion
  float* s6 = sb + 6 * HW;  // box temps
  float* s7 = sb + 7 * HW;
  float* s8 = sb + 8 * HW;
  float* s9 = sb + 9 * HW;

  dim3 blk(256);
  dim3 ge(GE);

  k0_init_dmin<<<ge, blk, 0, stream>>>(img, s0, st);
  k_minH<<<ge, blk, 0, stream>>>(s0, s1);
  k_minV<<<ge, blk, 0, stream>>>(s1, s0);

  for (int l = 0; l < 4; ++l)
    k_hist<<<ge, blk, 0, stream>>>(s0, st->histA, l, 230u, 1, 0);
  k_gatherA<<<ge, blk, 0, stream>>>(s0, img, st);
  k_finalizeA<<<dim3(1), blk, 0, stream>>>(img, st);

  k_elem1<<<ge, blk, 0, stream>>>(img, st, s2, s3, s4, s1);

  k_mega1<<<dim3(2048 + GE), blk, 0, stream>>>(s2, s3, s1, s5, st);
  k_mega2<<<dim3(2 * GE), blk, 0, stream>>>(st, s5, s0, s1);

  for (int l = 0; l < 4; ++l)
    k_hist<<<ge, blk, 0, stream>>>(s0, st->histB, l, 11521u, 0, 1);

  k_fusion<<<ge, blk, 0, stream>>>(s0, s1, st, s5);
  k_gf1h<<<ge, blk, 0, stream>>>(s4, s5, s6, s7, s8, s9);
  k_gf1v<<<ge, blk, 0, stream>>>(s6, s7, s8, s9, s2, s3);
  k_gf2h<<<ge, blk, 0, stream>>>(s2, s3, s6, s7);
  k_gf2vfin<<<ge, blk, 0, stream>>>(s6, s7, s4, img, st, out);
}